// Round 9
// baseline (316.353 us; speedup 1.0000x reference)
//
#include <hip/hip_runtime.h>
#include <cstdint>

// ---------------------------------------------------------------------------
// T-LSTM cell, fp32 in/out, split-bf16 MFMA.
// Round 13: R12 + (a) gate-selective W-lo, (b) compacted prep.
// (a) R12 showed MFMA is mostly hidden (25% MFMA cut -> only 3% time, with
//     MfmaUtil falling in proportion): the step critical path is staging +
//     ds_read + barrier. So cut STAGED/READ bytes: keep ah*bl only for
//     forgetgate (T-amplified) and cellgate (tanh linear-sensitive); in/out
//     gates pure-hi (bounded added error ~0.08). Wl is then consumed only at
//     B-rows 16-47/80-111 -> only waves 1,2 stage Wl (staging 32->28
//     gl_lds/block-step, Wl HBM fetch /4), ds_read 16->14 b128/wave/step,
//     MFMA 36->28/wave/step.
// (b) prep grid 8448 -> 2112 (each block loops 4 work items): fewer tiny
//     latency-bound blocks, non-gemm was ~82us vs ~30us ideal.
// Everything else identical to R12 (verified: 0 bank conflicts, natural bid
// order for W L2-residency, ptr-walk staging, 16-h gate interleave).
// ---------------------------------------------------------------------------

typedef __attribute__((ext_vector_type(8))) __bf16 bf16x8;
typedef __attribute__((ext_vector_type(4))) float f32x4;

__device__ __forceinline__ unsigned short f2bf_rn(float f) {
  unsigned int u = __float_as_uint(f);
  unsigned int r = u + 0x7fffu + ((u >> 16) & 1u);
  return (unsigned short)(r >> 16);
}
__device__ __forceinline__ float bf2f(unsigned short h) {
  return __uint_as_float(((unsigned int)h) << 16);
}
__device__ __forceinline__ float sigm_f(float x) {
  return 1.0f / (1.0f + __expf(-x));
}
__device__ __forceinline__ float tanh_f(float x) {
  return 1.0f - 2.0f / (__expf(2.0f * x) + 1.0f);
}
__device__ __forceinline__ void gl_lds16(const void* g, void* l) {
  __builtin_amdgcn_global_load_lds(
      (const __attribute__((address_space(1))) void*)g,
      (__attribute__((address_space(3))) void*)l, 16, 0, 0);
}
__device__ __forceinline__ void split4(const float* src,
                                       unsigned short* hi, unsigned short* lo) {
  float4 v = *(const float4*)src;
  ushort4 hv, lv;
  hv.x = f2bf_rn(v.x); lv.x = f2bf_rn(v.x - bf2f(hv.x));
  hv.y = f2bf_rn(v.y); lv.y = f2bf_rn(v.y - bf2f(hv.y));
  hv.z = f2bf_rn(v.z); lv.z = f2bf_rn(v.z - bf2f(hv.z));
  hv.w = f2bf_rn(v.w); lv.w = f2bf_rn(v.w - bf2f(hv.w));
  *(ushort4*)hi = hv;
  *(ushort4*)lo = lv;
}

// --- prep (compacted, 2112 blocks x 384 thr; each block = 4 work items):
// blocks [0,1024): X rows 4b..4b+3 (384 thr x 4) AND cx rows (256 thr x 4)
// blocks [1024,2048): W source rows 4..  -> dest row (h>>4)*64+g*16+(h&15)
// blocks [2048,2112): W_decomp 64x64 transpose tiles, 4 per block
__global__ __launch_bounds__(384) void prep_k(
    const float* __restrict__ input, const float* __restrict__ hx,
    const float* __restrict__ w_ih, const float* __restrict__ w_hh,
    const float* __restrict__ cx, const float* __restrict__ Wd,
    unsigned short* __restrict__ Xhi, unsigned short* __restrict__ Xlo,
    unsigned short* __restrict__ Whi, unsigned short* __restrict__ Wlo,
    unsigned short* __restrict__ Chi, unsigned short* __restrict__ Clo,
    unsigned short* __restrict__ Dhi, unsigned short* __restrict__ Dlo) {
  const int bid = blockIdx.x;
  const int k = threadIdx.x << 2;
  if (bid >= 2048) {
    // ---- transpose-split W_decomp [1024,1024] -> D[h][kk] = Wd[kk][h]
    __shared__ float tile[64][65];
    const int tx = threadIdx.x & 63;
    const int ty = threadIdx.x >> 6;  // 0..5
#pragma unroll 1
    for (int i = 0; i < 4; ++i) {
      const int tb = (bid - 2048) * 4 + i;
      const int bx = (tb & 15) * 64;
      const int by = (tb >> 4) * 64;
      for (int r = ty; r < 64; r += 6)
        tile[r][tx] = Wd[(long)(by + r) * 1024 + bx + tx];
      __syncthreads();
      for (int r = ty; r < 64; r += 6) {
        float v = tile[tx][r];  // = Wd[by+tx][bx+r]
        unsigned short h = f2bf_rn(v);
        long o = (long)(bx + r) * 1024 + by + tx;
        Dhi[o] = h;
        Dlo[o] = f2bf_rn(v - bf2f(h));
      }
      __syncthreads();  // tile reused next iteration
    }
    return;
  }
  if (bid < 1024) {
#pragma unroll 1
    for (int i = 0; i < 4; ++i) {
      const long m = (long)bid * 4 + i;
      const float* src =
          (k < 512) ? (input + m * 512 + k) : (hx + m * 1024 + (k - 512));
      split4(src, Xhi + m * 1536 + k, Xlo + m * 1536 + k);
      if (k < 1024)
        split4(cx + m * 1024 + k, Chi + m * 1024 + k, Clo + m * 1024 + k);
    }
  } else {
#pragma unroll 1
    for (int i = 0; i < 4; ++i) {
      const int n = (bid - 1024) * 4 + i;
      const int g = n >> 10;
      const int h = n & 1023;
      const long nd = ((long)(h >> 4) << 6) | (g << 4) | (h & 15);  // 16-h interleave
      const float* src =
          (k < 512) ? (w_ih + (long)n * 512 + k) : (w_hh + (long)n * 1024 + (k - 512));
      split4(src, Whi + nd * 1536 + k, Wlo + nd * 1536 + k);
    }
  }
}

// --- mega kernel: per block (m_blk, n_blk):
//   phase 1: dacc[4] = cx[128m] @ D[32h]^T  (K=1024, full 3-term split)
//   phase 2: acc[4][4] = X[128m] @ W'[128n']^T (K=1536); nf == gate
//            nf==1 (forget): ah*bh + ah*bl + al*bh (T-amplified path)
//            nf==2 (cell):   ah*bh + ah*bl        (tanh linear-sensitive)
//            nf in {0,3}:    ah*bh                (sigmoid, bounded)
//   epilogue: full T-LSTM pointwise -> hy, cy (direct to out)
// 256 thr, 4 waves 2Mx2N, wave tile 64x64 (4x4 16x16 frags).
// LDS swizzle (R3-verified, 0 conflicts): phys chunk p of row r holds logical
// chunk p^((r>>1)&3); staging lane L fetches logical (L&3)^((L>>3)&3).
__global__ __launch_bounds__(256) void gemm_mega(
    const unsigned short* __restrict__ Xh, const unsigned short* __restrict__ Xl,
    const unsigned short* __restrict__ Wh, const unsigned short* __restrict__ Wl,
    const unsigned short* __restrict__ Ch, const unsigned short* __restrict__ Cl,
    const unsigned short* __restrict__ Dh, const unsigned short* __restrict__ Dl,
    const float* __restrict__ b_ih, const float* __restrict__ b_hh,
    const float* __restrict__ b_d, const float* __restrict__ cx,
    const float* __restrict__ t, float* __restrict__ out) {
  __shared__ __align__(16) unsigned short sAh[128 * 32];
  __shared__ __align__(16) unsigned short sAl[128 * 32];
  __shared__ __align__(16) unsigned short sBh[128 * 32];
  __shared__ __align__(16) unsigned short sBl[128 * 32];

  // natural order (R4-proven): XCD x serves n_blk in {x, x+8, x+16, x+24}
  // for ALL m -> its 4 W-panels stay L2-resident the whole kernel.
  const int n_blk = blockIdx.x & 31;
  const int m_blk = blockIdx.x >> 5;
  const int m0 = m_blk * 128;
  const int n0 = n_blk * 128;  // interleaved-W row offset
  const int h0 = n_blk * 32;   // global h offset of this block

  const int tid = threadIdx.x;
  const int wave = tid >> 6;
  const int lane = tid & 63;
  const int wr = wave >> 1;   // 0..1 (M)
  const int wc = wave & 1;    // 0..1 (N)
  const int srow = lane >> 2;
  const int ssw = (((lane & 3) ^ ((lane >> 3) & 3)) << 3);  // bf16 elems
  const int fm = lane & 15;
  const int fq = lane >> 4;
  const int psw = (fq ^ ((fm >> 1) & 3)) << 3;

  // constant LDS staging destinations (per wave)
  unsigned short* const dA0h = sAh + (wave * 16) * 32;
  unsigned short* const dA0l = sAl + (wave * 16) * 32;
  unsigned short* const dA1h = sAh + (64 + wave * 16) * 32;
  unsigned short* const dA1l = sAl + (64 + wave * 16) * 32;
  unsigned short* const dB0h = sBh + (wave * 16) * 32;
  unsigned short* const dB0l = sBl + (wave * 16) * 32;
  unsigned short* const dB1h = sBh + (64 + wave * 16) * 32;
  unsigned short* const dB1l = sBl + (64 + wave * 16) * 32;

  // ---------------- phase 1: decomp  dacc = cx @ D^T ----------------
  f32x4 dacc[4];
#pragma unroll
  for (int i = 0; i < 4; ++i) dacc[i] = {0.f, 0.f, 0.f, 0.f};

  {
    const long aoff = (long)(m0 + wave * 16 + srow) * 1024 + ssw;
    const unsigned short* pAh0 = Ch + aoff;
    const unsigned short* pAl0 = Cl + aoff;
    const unsigned short* pAh1 = pAh0 + 64 * 1024;
    const unsigned short* pAl1 = pAl0 + 64 * 1024;
    const unsigned short* pD =
        ((wave & 2) ? Dl : Dh) + (long)(h0 + (wave & 1) * 16 + srow) * 1024 + ssw;
    unsigned short* const dD = ((wave & 2) ? sBl : sBh) + ((wave & 1) * 16) * 32;

    for (int kt = 0; kt < 1024; kt += 128) {
#pragma unroll
      for (int kk = 0; kk < 4; ++kk) {
        gl_lds16(pAh0 + kk * 32, dA0h);
        gl_lds16(pAl0 + kk * 32, dA0l);
        gl_lds16(pAh1 + kk * 32, dA1h);
        gl_lds16(pAl1 + kk * 32, dA1l);
        gl_lds16(pD + kk * 32, dD);
        __syncthreads();
        bf16x8 ah[4], al[4];
#pragma unroll
        for (int mf = 0; mf < 4; ++mf) {
          const int ao = (wr * 64 + mf * 16 + fm) * 32 + psw;
          ah[mf] = *(const bf16x8*)(sAh + ao);
          al[mf] = *(const bf16x8*)(sAl + ao);
        }
        const int bo = (wc * 16 + fm) * 32 + psw;
        const bf16x8 bh = *(const bf16x8*)(sBh + bo);
        const bf16x8 bl = *(const bf16x8*)(sBl + bo);
#pragma unroll
        for (int mf = 0; mf < 4; ++mf) {
          dacc[mf] = __builtin_amdgcn_mfma_f32_16x16x32_bf16(ah[mf], bh, dacc[mf], 0, 0, 0);
          dacc[mf] = __builtin_amdgcn_mfma_f32_16x16x32_bf16(ah[mf], bl, dacc[mf], 0, 0, 0);
          dacc[mf] = __builtin_amdgcn_mfma_f32_16x16x32_bf16(al[mf], bh, dacc[mf], 0, 0, 0);
        }
        __syncthreads();
      }
      pAh0 += 128; pAl0 += 128; pAh1 += 128; pAl1 += 128; pD += 128;
    }
  }

  // ---------------- phase 2: gates  acc = X @ W'^T ----------------
  f32x4 acc[4][4];
#pragma unroll
  for (int i = 0; i < 4; ++i)
#pragma unroll
    for (int j = 0; j < 4; ++j) acc[i][j] = {0.f, 0.f, 0.f, 0.f};

  {
    const long aoff = (long)(m0 + wave * 16 + srow) * 1536 + ssw;
    const long boff = (long)(n0 + wave * 16 + srow) * 1536 + ssw;
    const unsigned short* pXh0 = Xh + aoff;
    const unsigned short* pXl0 = Xl + aoff;
    const unsigned short* pXh1 = pXh0 + 64 * 1536;
    const unsigned short* pXl1 = pXl0 + 64 * 1536;
    const unsigned short* pWh0 = Wh + boff;
    const unsigned short* pWl0 = Wl + boff;
    const unsigned short* pWh1 = pWh0 + 64 * 1536;
    const unsigned short* pWl1 = pWl0 + 64 * 1536;
    // Wl consumed only at B-rows 16-47 (wc=0) / 80-111 (wc=1): waves 1,2 own
    // exactly those staging chunks (dB0l rows 16-31/32-47, dB1l 80-95/96-111).
    const bool stage_wl = (wave == 1) | (wave == 2);

    for (int kt = 0; kt < 1536; kt += 128) {
#pragma unroll
      for (int kk = 0; kk < 4; ++kk) {
        gl_lds16(pXh0 + kk * 32, dA0h);
        gl_lds16(pXl0 + kk * 32, dA0l);
        gl_lds16(pXh1 + kk * 32, dA1h);
        gl_lds16(pXl1 + kk * 32, dA1l);
        gl_lds16(pWh0 + kk * 32, dB0h);
        gl_lds16(pWh1 + kk * 32, dB1h);
        if (stage_wl) {
          gl_lds16(pWl0 + kk * 32, dB0l);
          gl_lds16(pWl1 + kk * 32, dB1l);
        }
        __syncthreads();
        bf16x8 ah[4], al[4], bh[4];
#pragma unroll
        for (int mf = 0; mf < 4; ++mf) {
          const int ao = (wr * 64 + mf * 16 + fm) * 32 + psw;
          ah[mf] = *(const bf16x8*)(sAh + ao);
          al[mf] = *(const bf16x8*)(sAl + ao);
        }
#pragma unroll
        for (int nf = 0; nf < 4; ++nf) {
          const int bo = (wc * 64 + nf * 16 + fm) * 32 + psw;
          bh[nf] = *(const bf16x8*)(sBh + bo);
        }
        const bf16x8 bl1 = *(const bf16x8*)(sBl + (wc * 64 + 16 + fm) * 32 + psw);
        const bf16x8 bl2 = *(const bf16x8*)(sBl + (wc * 64 + 32 + fm) * 32 + psw);
#pragma unroll
        for (int nf = 0; nf < 4; ++nf)
#pragma unroll
          for (int mf = 0; mf < 4; ++mf) {
            acc[mf][nf] = __builtin_amdgcn_mfma_f32_16x16x32_bf16(ah[mf], bh[nf], acc[mf][nf], 0, 0, 0);
            if (nf == 1) {  // forgetgate: T-amplified, full 3-term
              acc[mf][nf] = __builtin_amdgcn_mfma_f32_16x16x32_bf16(ah[mf], bl1, acc[mf][nf], 0, 0, 0);
              acc[mf][nf] = __builtin_amdgcn_mfma_f32_16x16x32_bf16(al[mf], bh[nf], acc[mf][nf], 0, 0, 0);
            }
            if (nf == 2)    // cellgate: tanh linear-sensitive, keep W-lo
              acc[mf][nf] = __builtin_amdgcn_mfma_f32_16x16x32_bf16(ah[mf], bl2, acc[mf][nf], 0, 0, 0);
          }
        __syncthreads();
      }
      pXh0 += 128; pXl0 += 128; pXh1 += 128; pXl1 += 128;
      pWh0 += 128; pWl0 += 128; pWh1 += 128; pWl1 += 128;
    }
  }

  // ---------------- epilogue: full T-LSTM pointwise ----------------
  // thread outputs: m = m0 + wr*64 + mf*16 + fq*4 + r ; h = h0 + wc*16 + fm
  // gate nf of acc[mf][nf][r]: 0=i 1=f 2=g 3=o
  const int h = h0 + wc * 16 + fm;
  const float bi  = b_ih[h]        + b_hh[h];
  const float bff = b_ih[1024 + h] + b_hh[1024 + h];
  const float bg  = b_ih[2048 + h] + b_hh[2048 + h];
  const float bo2 = b_ih[3072 + h] + b_hh[3072 + h];
  const float bd  = b_d[h];
#pragma unroll
  for (int mf = 0; mf < 4; ++mf) {
#pragma unroll
    for (int r = 0; r < 4; ++r) {
      const int m = m0 + wr * 64 + mf * 16 + fq * 4 + r;
      const float tv = t[m];
      const float T = (tv != 0.0f) ? (1.0f / tv) : 0.0f;
      const float cst = tanh_f(dacc[mf][r] + bd);
      const float cadj = cx[(long)m * 1024 + h] + (T - 1.0f) * cst;
      const float ig = sigm_f(acc[mf][0][r] + bi);
      const float fg = sigm_f(acc[mf][1][r] + bff);
      const float cg = tanh_f(acc[mf][2][r] + bg);
      const float og = sigm_f(acc[mf][3][r] + bo2);
      const float cyv = fg * cadj + ig * cg;
      const float hyv = og * tanh_f(cyv);
      out[(long)m * 1024 + h] = hyv;
      out[4096L * 1024 + (long)m * 1024 + h] = cyv;
    }
  }
}

extern "C" void kernel_launch(void* const* d_in, const int* in_sizes, int n_in,
                              void* d_out, int out_size, void* d_ws, size_t ws_size,
                              hipStream_t stream) {
  const float* input = (const float*)d_in[0];
  const float* t     = (const float*)d_in[1];
  const float* hx    = (const float*)d_in[2];
  const float* cx    = (const float*)d_in[3];
  const float* w_ih  = (const float*)d_in[4];
  const float* w_hh  = (const float*)d_in[5];
  const float* b_ih  = (const float*)d_in[6];
  const float* b_hh  = (const float*)d_in[7];
  const float* Wd    = (const float*)d_in[8];
  const float* b_d   = (const float*)d_in[9];

  const long B = 4096, H = 1024, KX = 1536, NG = 4096;

  char* ws = (char*)d_ws;
  unsigned short* Xhi = (unsigned short*)ws; ws += B * KX * 2;
  unsigned short* Xlo = (unsigned short*)ws; ws += B * KX * 2;
  unsigned short* Whi = (unsigned short*)ws; ws += NG * KX * 2;
  unsigned short* Wlo = (unsigned short*)ws; ws += NG * KX * 2;
  unsigned short* Chi = (unsigned short*)ws; ws += B * H * 2;
  unsigned short* Clo = (unsigned short*)ws; ws += B * H * 2;
  unsigned short* Dhi = (unsigned short*)ws; ws += H * H * 2;
  unsigned short* Dlo = (unsigned short*)ws; ws += H * H * 2;

  // 1: hi/lo splits (X+cx fused, W 16-h gate-interleaved) + W_decomp transpose
  prep_k<<<2112, 384, 0, stream>>>(input, hx, w_ih, w_hh, cx, Wd,
                                   Xhi, Xlo, Whi, Wlo, Chi, Clo, Dhi, Dlo);
  // 2: mega GEMM (decomp + gates + full pointwise epilogue)
  gemm_mega<<<1024, 256, 0, stream>>>(Xhi, Xlo, Whi, Wlo, Chi, Clo, Dhi, Dlo,
                                      b_ih, b_hh, b_d, cx, t, (float*)d_out);
}

// Round 10
// 291.770 us; speedup vs baseline: 1.0843x; 1.0843x over previous
//
#include <hip/hip_runtime.h>
#include <cstdint>

// ---------------------------------------------------------------------------
// T-LSTM cell, fp32 in/out, split-bf16 MFMA.
// Round 14: recombine proven halves. R13's A/B decomposed cleanly:
//  - gate-selective W-lo gemm: 231 -> 187us (staging/ds_read-bound confirmed)
//  - prep 4x compaction: non-gemm 82 -> 129us (serial per-block loop killed
//    TLP; the 8448 small blocks were providing latency hiding, not overhead)
// So: R12's prep (8448 blocks, ~82us) + R13's gemm (187us). No new mechanism.
// gemm: phase2 nf==1 (forget) 3-term, nf==2 (cell) 2-term +W-lo, nf in {0,3}
// pure-hi; only waves 1,2 stage Wl. Phase 1 full 3-term. 0 bank conflicts,
// natural bid order (W L2-resident), ptr-walk staging, 16-h gate interleave.
// ---------------------------------------------------------------------------

typedef __attribute__((ext_vector_type(8))) __bf16 bf16x8;
typedef __attribute__((ext_vector_type(4))) float f32x4;

__device__ __forceinline__ unsigned short f2bf_rn(float f) {
  unsigned int u = __float_as_uint(f);
  unsigned int r = u + 0x7fffu + ((u >> 16) & 1u);
  return (unsigned short)(r >> 16);
}
__device__ __forceinline__ float bf2f(unsigned short h) {
  return __uint_as_float(((unsigned int)h) << 16);
}
__device__ __forceinline__ float sigm_f(float x) {
  return 1.0f / (1.0f + __expf(-x));
}
__device__ __forceinline__ float tanh_f(float x) {
  return 1.0f - 2.0f / (__expf(2.0f * x) + 1.0f);
}
__device__ __forceinline__ void gl_lds16(const void* g, void* l) {
  __builtin_amdgcn_global_load_lds(
      (const __attribute__((address_space(1))) void*)g,
      (__attribute__((address_space(3))) void*)l, 16, 0, 0);
}

// --- prep (R12-proven): split X=[input|hx] + cx (fused), W (gate-interleaved),
//           and transpose-split W_decomp, one dispatch, 8448 blocks.
// blocks [0,4096): X row m (384 thr x 4) AND cx row m (256 thr x 4)
// blocks [4096,8192): W source row n -> dest row (h>>4)*64+g*16+(h&15)
// blocks [8192,8448): W_decomp 64x64 transpose tiles (384 thr, stride-6 rows)
__global__ __launch_bounds__(384) void prep_k(
    const float* __restrict__ input, const float* __restrict__ hx,
    const float* __restrict__ w_ih, const float* __restrict__ w_hh,
    const float* __restrict__ cx, const float* __restrict__ Wd,
    unsigned short* __restrict__ Xhi, unsigned short* __restrict__ Xlo,
    unsigned short* __restrict__ Whi, unsigned short* __restrict__ Wlo,
    unsigned short* __restrict__ Chi, unsigned short* __restrict__ Clo,
    unsigned short* __restrict__ Dhi, unsigned short* __restrict__ Dlo) {
  const int bid = blockIdx.x;
  const int k = threadIdx.x << 2;
  if (bid >= 8192) {
    // ---- transpose-split W_decomp [1024,1024] -> D[h][kk] = Wd[kk][h]
    __shared__ float tile[64][65];
    const int tb = bid - 8192;
    const int bx = (tb & 15) * 64;
    const int by = (tb >> 4) * 64;
    const int tx = threadIdx.x & 63;
    const int ty = threadIdx.x >> 6;  // 0..5
    for (int r = ty; r < 64; r += 6)
      tile[r][tx] = Wd[(long)(by + r) * 1024 + bx + tx];
    __syncthreads();
    for (int r = ty; r < 64; r += 6) {
      float v = tile[tx][r];  // = Wd[by+tx][bx+r]
      unsigned short h = f2bf_rn(v);
      long o = (long)(bx + r) * 1024 + by + tx;
      Dhi[o] = h;
      Dlo[o] = f2bf_rn(v - bf2f(h));
    }
    return;
  }
  const float* src;
  unsigned short *hi, *lo;
  if (bid < 4096) {
    const long m = bid;
    // part 1: X = [input | hx]
    src = (k < 512) ? (input + m * 512 + k) : (hx + m * 1024 + (k - 512));
    hi = Xhi + m * 1536 + k;
    lo = Xlo + m * 1536 + k;
    {
      float4 v = *(const float4*)src;
      ushort4 hv, lv;
      hv.x = f2bf_rn(v.x); lv.x = f2bf_rn(v.x - bf2f(hv.x));
      hv.y = f2bf_rn(v.y); lv.y = f2bf_rn(v.y - bf2f(hv.y));
      hv.z = f2bf_rn(v.z); lv.z = f2bf_rn(v.z - bf2f(hv.z));
      hv.w = f2bf_rn(v.w); lv.w = f2bf_rn(v.w - bf2f(hv.w));
      *(ushort4*)hi = hv;
      *(ushort4*)lo = lv;
    }
    // part 2: cx (first 256 threads)
    if (k >= 1024) return;
    src = cx + m * 1024 + k;
    hi = Chi + m * 1024 + k;
    lo = Clo + m * 1024 + k;
  } else {
    const int n = bid - 4096;
    const int g = n >> 10;
    const int h = n & 1023;
    const long nd = ((long)(h >> 4) << 6) | (g << 4) | (h & 15);  // 16-h interleave
    src = (k < 512) ? (w_ih + (long)n * 512 + k) : (w_hh + (long)n * 1024 + (k - 512));
    hi = Whi + nd * 1536 + k;
    lo = Wlo + nd * 1536 + k;
  }
  float4 v = *(const float4*)src;
  ushort4 hv, lv;
  hv.x = f2bf_rn(v.x); lv.x = f2bf_rn(v.x - bf2f(hv.x));
  hv.y = f2bf_rn(v.y); lv.y = f2bf_rn(v.y - bf2f(hv.y));
  hv.z = f2bf_rn(v.z); lv.z = f2bf_rn(v.z - bf2f(hv.z));
  hv.w = f2bf_rn(v.w); lv.w = f2bf_rn(v.w - bf2f(hv.w));
  *(ushort4*)hi = hv;
  *(ushort4*)lo = lv;
}

// --- mega kernel (R13-proven): per block (m_blk, n_blk):
//   phase 1: dacc[4] = cx[128m] @ D[32h]^T  (K=1024, full 3-term split)
//   phase 2: acc[4][4] = X[128m] @ W'[128n']^T (K=1536); nf == gate
//            nf==1 (forget): ah*bh + ah*bl + al*bh (T-amplified path)
//            nf==2 (cell):   ah*bh + ah*bl        (tanh linear-sensitive)
//            nf in {0,3}:    ah*bh                (sigmoid, bounded)
//   epilogue: full T-LSTM pointwise -> hy, cy (direct to out)
// 256 thr, 4 waves 2Mx2N, wave tile 64x64 (4x4 16x16 frags).
// LDS swizzle (R3-verified, 0 conflicts): phys chunk p of row r holds logical
// chunk p^((r>>1)&3); staging lane L fetches logical (L&3)^((L>>3)&3).
__global__ __launch_bounds__(256) void gemm_mega(
    const unsigned short* __restrict__ Xh, const unsigned short* __restrict__ Xl,
    const unsigned short* __restrict__ Wh, const unsigned short* __restrict__ Wl,
    const unsigned short* __restrict__ Ch, const unsigned short* __restrict__ Cl,
    const unsigned short* __restrict__ Dh, const unsigned short* __restrict__ Dl,
    const float* __restrict__ b_ih, const float* __restrict__ b_hh,
    const float* __restrict__ b_d, const float* __restrict__ cx,
    const float* __restrict__ t, float* __restrict__ out) {
  __shared__ __align__(16) unsigned short sAh[128 * 32];
  __shared__ __align__(16) unsigned short sAl[128 * 32];
  __shared__ __align__(16) unsigned short sBh[128 * 32];
  __shared__ __align__(16) unsigned short sBl[128 * 32];

  // natural order (R4-proven): XCD x serves n_blk in {x, x+8, x+16, x+24}
  // for ALL m -> its 4 W-panels stay L2-resident the whole kernel.
  const int n_blk = blockIdx.x & 31;
  const int m_blk = blockIdx.x >> 5;
  const int m0 = m_blk * 128;
  const int n0 = n_blk * 128;  // interleaved-W row offset
  const int h0 = n_blk * 32;   // global h offset of this block

  const int tid = threadIdx.x;
  const int wave = tid >> 6;
  const int lane = tid & 63;
  const int wr = wave >> 1;   // 0..1 (M)
  const int wc = wave & 1;    // 0..1 (N)
  const int srow = lane >> 2;
  const int ssw = (((lane & 3) ^ ((lane >> 3) & 3)) << 3);  // bf16 elems
  const int fm = lane & 15;
  const int fq = lane >> 4;
  const int psw = (fq ^ ((fm >> 1) & 3)) << 3;

  // constant LDS staging destinations (per wave)
  unsigned short* const dA0h = sAh + (wave * 16) * 32;
  unsigned short* const dA0l = sAl + (wave * 16) * 32;
  unsigned short* const dA1h = sAh + (64 + wave * 16) * 32;
  unsigned short* const dA1l = sAl + (64 + wave * 16) * 32;
  unsigned short* const dB0h = sBh + (wave * 16) * 32;
  unsigned short* const dB0l = sBl + (wave * 16) * 32;
  unsigned short* const dB1h = sBh + (64 + wave * 16) * 32;
  unsigned short* const dB1l = sBl + (64 + wave * 16) * 32;

  // ---------------- phase 1: decomp  dacc = cx @ D^T ----------------
  f32x4 dacc[4];
#pragma unroll
  for (int i = 0; i < 4; ++i) dacc[i] = {0.f, 0.f, 0.f, 0.f};

  {
    const long aoff = (long)(m0 + wave * 16 + srow) * 1024 + ssw;
    const unsigned short* pAh0 = Ch + aoff;
    const unsigned short* pAl0 = Cl + aoff;
    const unsigned short* pAh1 = pAh0 + 64 * 1024;
    const unsigned short* pAl1 = pAl0 + 64 * 1024;
    const unsigned short* pD =
        ((wave & 2) ? Dl : Dh) + (long)(h0 + (wave & 1) * 16 + srow) * 1024 + ssw;
    unsigned short* const dD = ((wave & 2) ? sBl : sBh) + ((wave & 1) * 16) * 32;

    for (int kt = 0; kt < 1024; kt += 128) {
#pragma unroll
      for (int kk = 0; kk < 4; ++kk) {
        gl_lds16(pAh0 + kk * 32, dA0h);
        gl_lds16(pAl0 + kk * 32, dA0l);
        gl_lds16(pAh1 + kk * 32, dA1h);
        gl_lds16(pAl1 + kk * 32, dA1l);
        gl_lds16(pD + kk * 32, dD);
        __syncthreads();
        bf16x8 ah[4], al[4];
#pragma unroll
        for (int mf = 0; mf < 4; ++mf) {
          const int ao = (wr * 64 + mf * 16 + fm) * 32 + psw;
          ah[mf] = *(const bf16x8*)(sAh + ao);
          al[mf] = *(const bf16x8*)(sAl + ao);
        }
        const int bo = (wc * 16 + fm) * 32 + psw;
        const bf16x8 bh = *(const bf16x8*)(sBh + bo);
        const bf16x8 bl = *(const bf16x8*)(sBl + bo);
#pragma unroll
        for (int mf = 0; mf < 4; ++mf) {
          dacc[mf] = __builtin_amdgcn_mfma_f32_16x16x32_bf16(ah[mf], bh, dacc[mf], 0, 0, 0);
          dacc[mf] = __builtin_amdgcn_mfma_f32_16x16x32_bf16(ah[mf], bl, dacc[mf], 0, 0, 0);
          dacc[mf] = __builtin_amdgcn_mfma_f32_16x16x32_bf16(al[mf], bh, dacc[mf], 0, 0, 0);
        }
        __syncthreads();
      }
      pAh0 += 128; pAl0 += 128; pAh1 += 128; pAl1 += 128; pD += 128;
    }
  }

  // ---------------- phase 2: gates  acc = X @ W'^T ----------------
  f32x4 acc[4][4];
#pragma unroll
  for (int i = 0; i < 4; ++i)
#pragma unroll
    for (int j = 0; j < 4; ++j) acc[i][j] = {0.f, 0.f, 0.f, 0.f};

  {
    const long aoff = (long)(m0 + wave * 16 + srow) * 1536 + ssw;
    const long boff = (long)(n0 + wave * 16 + srow) * 1536 + ssw;
    const unsigned short* pXh0 = Xh + aoff;
    const unsigned short* pXl0 = Xl + aoff;
    const unsigned short* pXh1 = pXh0 + 64 * 1536;
    const unsigned short* pXl1 = pXl0 + 64 * 1536;
    const unsigned short* pWh0 = Wh + boff;
    const unsigned short* pWl0 = Wl + boff;
    const unsigned short* pWh1 = pWh0 + 64 * 1536;
    const unsigned short* pWl1 = pWl0 + 64 * 1536;
    // Wl consumed only at B-rows 16-47 (wc=0) / 80-111 (wc=1): waves 1,2 own
    // exactly those staging chunks (dB0l rows 16-31/32-47, dB1l 80-95/96-111).
    const bool stage_wl = (wave == 1) | (wave == 2);

    for (int kt = 0; kt < 1536; kt += 128) {
#pragma unroll
      for (int kk = 0; kk < 4; ++kk) {
        gl_lds16(pXh0 + kk * 32, dA0h);
        gl_lds16(pXl0 + kk * 32, dA0l);
        gl_lds16(pXh1 + kk * 32, dA1h);
        gl_lds16(pXl1 + kk * 32, dA1l);
        gl_lds16(pWh0 + kk * 32, dB0h);
        gl_lds16(pWh1 + kk * 32, dB1h);
        if (stage_wl) {
          gl_lds16(pWl0 + kk * 32, dB0l);
          gl_lds16(pWl1 + kk * 32, dB1l);
        }
        __syncthreads();
        bf16x8 ah[4], al[4], bh[4];
#pragma unroll
        for (int mf = 0; mf < 4; ++mf) {
          const int ao = (wr * 64 + mf * 16 + fm) * 32 + psw;
          ah[mf] = *(const bf16x8*)(sAh + ao);
          al[mf] = *(const bf16x8*)(sAl + ao);
        }
#pragma unroll
        for (int nf = 0; nf < 4; ++nf) {
          const int bo = (wc * 64 + nf * 16 + fm) * 32 + psw;
          bh[nf] = *(const bf16x8*)(sBh + bo);
        }
        const bf16x8 bl1 = *(const bf16x8*)(sBl + (wc * 64 + 16 + fm) * 32 + psw);
        const bf16x8 bl2 = *(const bf16x8*)(sBl + (wc * 64 + 32 + fm) * 32 + psw);
#pragma unroll
        for (int nf = 0; nf < 4; ++nf)
#pragma unroll
          for (int mf = 0; mf < 4; ++mf) {
            acc[mf][nf] = __builtin_amdgcn_mfma_f32_16x16x32_bf16(ah[mf], bh[nf], acc[mf][nf], 0, 0, 0);
            if (nf == 1) {  // forgetgate: T-amplified, full 3-term
              acc[mf][nf] = __builtin_amdgcn_mfma_f32_16x16x32_bf16(ah[mf], bl1, acc[mf][nf], 0, 0, 0);
              acc[mf][nf] = __builtin_amdgcn_mfma_f32_16x16x32_bf16(al[mf], bh[nf], acc[mf][nf], 0, 0, 0);
            }
            if (nf == 2)    // cellgate: tanh linear-sensitive, keep W-lo
              acc[mf][nf] = __builtin_amdgcn_mfma_f32_16x16x32_bf16(ah[mf], bl2, acc[mf][nf], 0, 0, 0);
          }
        __syncthreads();
      }
      pXh0 += 128; pXl0 += 128; pXh1 += 128; pXl1 += 128;
      pWh0 += 128; pWl0 += 128; pWh1 += 128; pWl1 += 128;
    }
  }

  // ---------------- epilogue: full T-LSTM pointwise ----------------
  // thread outputs: m = m0 + wr*64 + mf*16 + fq*4 + r ; h = h0 + wc*16 + fm
  // gate nf of acc[mf][nf][r]: 0=i 1=f 2=g 3=o
  const int h = h0 + wc * 16 + fm;
  const float bi  = b_ih[h]        + b_hh[h];
  const float bff = b_ih[1024 + h] + b_hh[1024 + h];
  const float bg  = b_ih[2048 + h] + b_hh[2048 + h];
  const float bo2 = b_ih[3072 + h] + b_hh[3072 + h];
  const float bd  = b_d[h];
#pragma unroll
  for (int mf = 0; mf < 4; ++mf) {
#pragma unroll
    for (int r = 0; r < 4; ++r) {
      const int m = m0 + wr * 64 + mf * 16 + fq * 4 + r;
      const float tv = t[m];
      const float T = (tv != 0.0f) ? (1.0f / tv) : 0.0f;
      const float cst = tanh_f(dacc[mf][r] + bd);
      const float cadj = cx[(long)m * 1024 + h] + (T - 1.0f) * cst;
      const float ig = sigm_f(acc[mf][0][r] + bi);
      const float fg = sigm_f(acc[mf][1][r] + bff);
      const float cg = tanh_f(acc[mf][2][r] + bg);
      const float og = sigm_f(acc[mf][3][r] + bo2);
      const float cyv = fg * cadj + ig * cg;
      const float hyv = og * tanh_f(cyv);
      out[(long)m * 1024 + h] = hyv;
      out[4096L * 1024 + (long)m * 1024 + h] = cyv;
    }
  }
}

extern "C" void kernel_launch(void* const* d_in, const int* in_sizes, int n_in,
                              void* d_out, int out_size, void* d_ws, size_t ws_size,
                              hipStream_t stream) {
  const float* input = (const float*)d_in[0];
  const float* t     = (const float*)d_in[1];
  const float* hx    = (const float*)d_in[2];
  const float* cx    = (const float*)d_in[3];
  const float* w_ih  = (const float*)d_in[4];
  const float* w_hh  = (const float*)d_in[5];
  const float* b_ih  = (const float*)d_in[6];
  const float* b_hh  = (const float*)d_in[7];
  const float* Wd    = (const float*)d_in[8];
  const float* b_d   = (const float*)d_in[9];

  const long B = 4096, H = 1024, KX = 1536, NG = 4096;

  char* ws = (char*)d_ws;
  unsigned short* Xhi = (unsigned short*)ws; ws += B * KX * 2;
  unsigned short* Xlo = (unsigned short*)ws; ws += B * KX * 2;
  unsigned short* Whi = (unsigned short*)ws; ws += NG * KX * 2;
  unsigned short* Wlo = (unsigned short*)ws; ws += NG * KX * 2;
  unsigned short* Chi = (unsigned short*)ws; ws += B * H * 2;
  unsigned short* Clo = (unsigned short*)ws; ws += B * H * 2;
  unsigned short* Dhi = (unsigned short*)ws; ws += H * H * 2;
  unsigned short* Dlo = (unsigned short*)ws; ws += H * H * 2;

  // 1: hi/lo splits (X+cx fused, W 16-h gate-interleaved) + W_decomp transpose
  prep_k<<<8448, 384, 0, stream>>>(input, hx, w_ih, w_hh, cx, Wd,
                                   Xhi, Xlo, Whi, Wlo, Chi, Clo, Dhi, Dlo);
  // 2: mega GEMM (decomp + gates gate-selective + full pointwise epilogue)
  gemm_mega<<<1024, 256, 0, stream>>>(Xhi, Xlo, Whi, Wlo, Chi, Clo, Dhi, Dlo,
                                      b_ih, b_hh, b_d, cx, t, (float*)d_out);
}

// Round 11
// 290.597 us; speedup vs baseline: 1.0886x; 1.0040x over previous
//
#include <hip/hip_runtime.h>
#include <cstdint>

// ---------------------------------------------------------------------------
// T-LSTM cell, fp32 in/out, split-bf16 MFMA.
// Round 15: R14 gemm (byte-identical, 187us proven x2 sessions) + prep with
// explicit memory-level parallelism. R13's compaction failed because
// `#pragma unroll 1` serialized the 4 per-block work items (4x exposed HBM
// latency); here each block handles 4 rows with ALL loads batched up front
// (4-8 independent dwordx4 in flight per thread), then converts+stores.
// Also: Wlo rows with gate g in {0,3} are never staged/read by the
// gate-selective gemm -> skip writing them (-12.6MB writes).
// Grid: 1024 X/cx blocks (4 rows each) + 1024 W blocks (4 rows each) +
// 256 transpose blocks (1 tile each, R14-proven) = 2304.
// ---------------------------------------------------------------------------

typedef __attribute__((ext_vector_type(8))) __bf16 bf16x8;
typedef __attribute__((ext_vector_type(4))) float f32x4;

__device__ __forceinline__ unsigned short f2bf_rn(float f) {
  unsigned int u = __float_as_uint(f);
  unsigned int r = u + 0x7fffu + ((u >> 16) & 1u);
  return (unsigned short)(r >> 16);
}
__device__ __forceinline__ float bf2f(unsigned short h) {
  return __uint_as_float(((unsigned int)h) << 16);
}
__device__ __forceinline__ float sigm_f(float x) {
  return 1.0f / (1.0f + __expf(-x));
}
__device__ __forceinline__ float tanh_f(float x) {
  return 1.0f - 2.0f / (__expf(2.0f * x) + 1.0f);
}
__device__ __forceinline__ void gl_lds16(const void* g, void* l) {
  __builtin_amdgcn_global_load_lds(
      (const __attribute__((address_space(1))) void*)g,
      (__attribute__((address_space(3))) void*)l, 16, 0, 0);
}
__device__ __forceinline__ void split_store(float4 v, unsigned short* hi,
                                            unsigned short* lo) {
  ushort4 hv, lv;
  hv.x = f2bf_rn(v.x); lv.x = f2bf_rn(v.x - bf2f(hv.x));
  hv.y = f2bf_rn(v.y); lv.y = f2bf_rn(v.y - bf2f(hv.y));
  hv.z = f2bf_rn(v.z); lv.z = f2bf_rn(v.z - bf2f(hv.z));
  hv.w = f2bf_rn(v.w); lv.w = f2bf_rn(v.w - bf2f(hv.w));
  *(ushort4*)hi = hv;
  *(ushort4*)lo = lv;
}

// --- prep: 2304 blocks x 384 thr.
// blocks [0,1024): X rows 4b..4b+3 (batched loads) + cx rows (256 thr)
// blocks [1024,2048): W rows 4..: dest row (h>>4)*64+g*16+(h&15);
//                     Wlo written only for g in {1,2}
// blocks [2048,2304): W_decomp 64x64 transpose tile each
__global__ __launch_bounds__(384) void prep_k(
    const float* __restrict__ input, const float* __restrict__ hx,
    const float* __restrict__ w_ih, const float* __restrict__ w_hh,
    const float* __restrict__ cx, const float* __restrict__ Wd,
    unsigned short* __restrict__ Xhi, unsigned short* __restrict__ Xlo,
    unsigned short* __restrict__ Whi, unsigned short* __restrict__ Wlo,
    unsigned short* __restrict__ Chi, unsigned short* __restrict__ Clo,
    unsigned short* __restrict__ Dhi, unsigned short* __restrict__ Dlo) {
  const int bid = blockIdx.x;
  const int k = threadIdx.x << 2;
  if (bid < 1024) {
    const long mb = (long)bid * 4;
    // batch all loads first: 4x X (+4x cx for k<1024) independent dwordx4
    float4 xv[4];
#pragma unroll
    for (int i = 0; i < 4; ++i) {
      const long m = mb + i;
      const float* src =
          (k < 512) ? (input + m * 512 + k) : (hx + m * 1024 + (k - 512));
      xv[i] = *(const float4*)src;
    }
    const bool do_cx = (k < 1024);
    float4 cv[4];
    if (do_cx) {
#pragma unroll
      for (int i = 0; i < 4; ++i)
        cv[i] = *(const float4*)(cx + (mb + i) * 1024 + k);
    }
#pragma unroll
    for (int i = 0; i < 4; ++i)
      split_store(xv[i], Xhi + (mb + i) * 1536 + k, Xlo + (mb + i) * 1536 + k);
    if (do_cx) {
#pragma unroll
      for (int i = 0; i < 4; ++i)
        split_store(cv[i], Chi + (mb + i) * 1024 + k, Clo + (mb + i) * 1024 + k);
    }
  } else if (bid < 2048) {
    const int nb = (bid - 1024) * 4;
    float4 wv[4];
#pragma unroll
    for (int i = 0; i < 4; ++i) {
      const int n = nb + i;
      const float* src =
          (k < 512) ? (w_ih + (long)n * 512 + k) : (w_hh + (long)n * 1024 + (k - 512));
      wv[i] = *(const float4*)src;
    }
#pragma unroll
    for (int i = 0; i < 4; ++i) {
      const int n = nb + i;
      const int g = n >> 10;
      const int h = n & 1023;
      const long nd = ((long)(h >> 4) << 6) | (g << 4) | (h & 15);  // 16-h interleave
      float4 v = wv[i];
      ushort4 hv, lv;
      hv.x = f2bf_rn(v.x); lv.x = f2bf_rn(v.x - bf2f(hv.x));
      hv.y = f2bf_rn(v.y); lv.y = f2bf_rn(v.y - bf2f(hv.y));
      hv.z = f2bf_rn(v.z); lv.z = f2bf_rn(v.z - bf2f(hv.z));
      hv.w = f2bf_rn(v.w); lv.w = f2bf_rn(v.w - bf2f(hv.w));
      *(ushort4*)(Whi + nd * 1536 + k) = hv;
      if (g == 1 || g == 2)  // Wlo only consumed for forget/cell gates
        *(ushort4*)(Wlo + nd * 1536 + k) = lv;
    }
  } else {
    // ---- transpose-split W_decomp [1024,1024] -> D[h][kk] = Wd[kk][h]
    __shared__ float tile[64][65];
    const int tb = bid - 2048;
    const int bx = (tb & 15) * 64;
    const int by = (tb >> 4) * 64;
    const int tx = threadIdx.x & 63;
    const int ty = threadIdx.x >> 6;  // 0..5
    for (int r = ty; r < 64; r += 6)
      tile[r][tx] = Wd[(long)(by + r) * 1024 + bx + tx];
    __syncthreads();
    for (int r = ty; r < 64; r += 6) {
      float v = tile[tx][r];  // = Wd[by+tx][bx+r]
      unsigned short h = f2bf_rn(v);
      long o = (long)(bx + r) * 1024 + by + tx;
      Dhi[o] = h;
      Dlo[o] = f2bf_rn(v - bf2f(h));
    }
  }
}

// --- mega kernel (R13/R14-proven, byte-identical): per block (m_blk, n_blk):
//   phase 1: dacc[4] = cx[128m] @ D[32h]^T  (K=1024, full 3-term split)
//   phase 2: acc[4][4] = X[128m] @ W'[128n']^T (K=1536); nf == gate
//            nf==1 (forget): ah*bh + ah*bl + al*bh (T-amplified path)
//            nf==2 (cell):   ah*bh + ah*bl        (tanh linear-sensitive)
//            nf in {0,3}:    ah*bh                (sigmoid, bounded)
//   epilogue: full T-LSTM pointwise -> hy, cy (direct to out)
// 256 thr, 4 waves 2Mx2N, wave tile 64x64 (4x4 16x16 frags).
// LDS swizzle (R3-verified, 0 conflicts): phys chunk p of row r holds logical
// chunk p^((r>>1)&3); staging lane L fetches logical (L&3)^((L>>3)&3).
__global__ __launch_bounds__(256) void gemm_mega(
    const unsigned short* __restrict__ Xh, const unsigned short* __restrict__ Xl,
    const unsigned short* __restrict__ Wh, const unsigned short* __restrict__ Wl,
    const unsigned short* __restrict__ Ch, const unsigned short* __restrict__ Cl,
    const unsigned short* __restrict__ Dh, const unsigned short* __restrict__ Dl,
    const float* __restrict__ b_ih, const float* __restrict__ b_hh,
    const float* __restrict__ b_d, const float* __restrict__ cx,
    const float* __restrict__ t, float* __restrict__ out) {
  __shared__ __align__(16) unsigned short sAh[128 * 32];
  __shared__ __align__(16) unsigned short sAl[128 * 32];
  __shared__ __align__(16) unsigned short sBh[128 * 32];
  __shared__ __align__(16) unsigned short sBl[128 * 32];

  // natural order (R4-proven): XCD x serves n_blk in {x, x+8, x+16, x+24}
  // for ALL m -> its 4 W-panels stay L2-resident the whole kernel.
  const int n_blk = blockIdx.x & 31;
  const int m_blk = blockIdx.x >> 5;
  const int m0 = m_blk * 128;
  const int n0 = n_blk * 128;  // interleaved-W row offset
  const int h0 = n_blk * 32;   // global h offset of this block

  const int tid = threadIdx.x;
  const int wave = tid >> 6;
  const int lane = tid & 63;
  const int wr = wave >> 1;   // 0..1 (M)
  const int wc = wave & 1;    // 0..1 (N)
  const int srow = lane >> 2;
  const int ssw = (((lane & 3) ^ ((lane >> 3) & 3)) << 3);  // bf16 elems
  const int fm = lane & 15;
  const int fq = lane >> 4;
  const int psw = (fq ^ ((fm >> 1) & 3)) << 3;

  // constant LDS staging destinations (per wave)
  unsigned short* const dA0h = sAh + (wave * 16) * 32;
  unsigned short* const dA0l = sAl + (wave * 16) * 32;
  unsigned short* const dA1h = sAh + (64 + wave * 16) * 32;
  unsigned short* const dA1l = sAl + (64 + wave * 16) * 32;
  unsigned short* const dB0h = sBh + (wave * 16) * 32;
  unsigned short* const dB0l = sBl + (wave * 16) * 32;
  unsigned short* const dB1h = sBh + (64 + wave * 16) * 32;
  unsigned short* const dB1l = sBl + (64 + wave * 16) * 32;

  // ---------------- phase 1: decomp  dacc = cx @ D^T ----------------
  f32x4 dacc[4];
#pragma unroll
  for (int i = 0; i < 4; ++i) dacc[i] = {0.f, 0.f, 0.f, 0.f};

  {
    const long aoff = (long)(m0 + wave * 16 + srow) * 1024 + ssw;
    const unsigned short* pAh0 = Ch + aoff;
    const unsigned short* pAl0 = Cl + aoff;
    const unsigned short* pAh1 = pAh0 + 64 * 1024;
    const unsigned short* pAl1 = pAl0 + 64 * 1024;
    const unsigned short* pD =
        ((wave & 2) ? Dl : Dh) + (long)(h0 + (wave & 1) * 16 + srow) * 1024 + ssw;
    unsigned short* const dD = ((wave & 2) ? sBl : sBh) + ((wave & 1) * 16) * 32;

    for (int kt = 0; kt < 1024; kt += 128) {
#pragma unroll
      for (int kk = 0; kk < 4; ++kk) {
        gl_lds16(pAh0 + kk * 32, dA0h);
        gl_lds16(pAl0 + kk * 32, dA0l);
        gl_lds16(pAh1 + kk * 32, dA1h);
        gl_lds16(pAl1 + kk * 32, dA1l);
        gl_lds16(pD + kk * 32, dD);
        __syncthreads();
        bf16x8 ah[4], al[4];
#pragma unroll
        for (int mf = 0; mf < 4; ++mf) {
          const int ao = (wr * 64 + mf * 16 + fm) * 32 + psw;
          ah[mf] = *(const bf16x8*)(sAh + ao);
          al[mf] = *(const bf16x8*)(sAl + ao);
        }
        const int bo = (wc * 16 + fm) * 32 + psw;
        const bf16x8 bh = *(const bf16x8*)(sBh + bo);
        const bf16x8 bl = *(const bf16x8*)(sBl + bo);
#pragma unroll
        for (int mf = 0; mf < 4; ++mf) {
          dacc[mf] = __builtin_amdgcn_mfma_f32_16x16x32_bf16(ah[mf], bh, dacc[mf], 0, 0, 0);
          dacc[mf] = __builtin_amdgcn_mfma_f32_16x16x32_bf16(ah[mf], bl, dacc[mf], 0, 0, 0);
          dacc[mf] = __builtin_amdgcn_mfma_f32_16x16x32_bf16(al[mf], bh, dacc[mf], 0, 0, 0);
        }
        __syncthreads();
      }
      pAh0 += 128; pAl0 += 128; pAh1 += 128; pAl1 += 128; pD += 128;
    }
  }

  // ---------------- phase 2: gates  acc = X @ W'^T ----------------
  f32x4 acc[4][4];
#pragma unroll
  for (int i = 0; i < 4; ++i)
#pragma unroll
    for (int j = 0; j < 4; ++j) acc[i][j] = {0.f, 0.f, 0.f, 0.f};

  {
    const long aoff = (long)(m0 + wave * 16 + srow) * 1536 + ssw;
    const long boff = (long)(n0 + wave * 16 + srow) * 1536 + ssw;
    const unsigned short* pXh0 = Xh + aoff;
    const unsigned short* pXl0 = Xl + aoff;
    const unsigned short* pXh1 = pXh0 + 64 * 1536;
    const unsigned short* pXl1 = pXl0 + 64 * 1536;
    const unsigned short* pWh0 = Wh + boff;
    const unsigned short* pWl0 = Wl + boff;
    const unsigned short* pWh1 = pWh0 + 64 * 1536;
    const unsigned short* pWl1 = pWl0 + 64 * 1536;
    // Wl consumed only at B-rows 16-47 (wc=0) / 80-111 (wc=1): waves 1,2 own
    // exactly those staging chunks (dB0l rows 16-31/32-47, dB1l 80-95/96-111).
    const bool stage_wl = (wave == 1) | (wave == 2);

    for (int kt = 0; kt < 1536; kt += 128) {
#pragma unroll
      for (int kk = 0; kk < 4; ++kk) {
        gl_lds16(pXh0 + kk * 32, dA0h);
        gl_lds16(pXl0 + kk * 32, dA0l);
        gl_lds16(pXh1 + kk * 32, dA1h);
        gl_lds16(pXl1 + kk * 32, dA1l);
        gl_lds16(pWh0 + kk * 32, dB0h);
        gl_lds16(pWh1 + kk * 32, dB1h);
        if (stage_wl) {
          gl_lds16(pWl0 + kk * 32, dB0l);
          gl_lds16(pWl1 + kk * 32, dB1l);
        }
        __syncthreads();
        bf16x8 ah[4], al[4], bh[4];
#pragma unroll
        for (int mf = 0; mf < 4; ++mf) {
          const int ao = (wr * 64 + mf * 16 + fm) * 32 + psw;
          ah[mf] = *(const bf16x8*)(sAh + ao);
          al[mf] = *(const bf16x8*)(sAl + ao);
        }
#pragma unroll
        for (int nf = 0; nf < 4; ++nf) {
          const int bo = (wc * 64 + nf * 16 + fm) * 32 + psw;
          bh[nf] = *(const bf16x8*)(sBh + bo);
        }
        const bf16x8 bl1 = *(const bf16x8*)(sBl + (wc * 64 + 16 + fm) * 32 + psw);
        const bf16x8 bl2 = *(const bf16x8*)(sBl + (wc * 64 + 32 + fm) * 32 + psw);
#pragma unroll
        for (int nf = 0; nf < 4; ++nf)
#pragma unroll
          for (int mf = 0; mf < 4; ++mf) {
            acc[mf][nf] = __builtin_amdgcn_mfma_f32_16x16x32_bf16(ah[mf], bh[nf], acc[mf][nf], 0, 0, 0);
            if (nf == 1) {  // forgetgate: T-amplified, full 3-term
              acc[mf][nf] = __builtin_amdgcn_mfma_f32_16x16x32_bf16(ah[mf], bl1, acc[mf][nf], 0, 0, 0);
              acc[mf][nf] = __builtin_amdgcn_mfma_f32_16x16x32_bf16(al[mf], bh[nf], acc[mf][nf], 0, 0, 0);
            }
            if (nf == 2)    // cellgate: tanh linear-sensitive, keep W-lo
              acc[mf][nf] = __builtin_amdgcn_mfma_f32_16x16x32_bf16(ah[mf], bl2, acc[mf][nf], 0, 0, 0);
          }
        __syncthreads();
      }
      pXh0 += 128; pXl0 += 128; pXh1 += 128; pXl1 += 128;
      pWh0 += 128; pWl0 += 128; pWh1 += 128; pWl1 += 128;
    }
  }

  // ---------------- epilogue: full T-LSTM pointwise ----------------
  // thread outputs: m = m0 + wr*64 + mf*16 + fq*4 + r ; h = h0 + wc*16 + fm
  // gate nf of acc[mf][nf][r]: 0=i 1=f 2=g 3=o
  const int h = h0 + wc * 16 + fm;
  const float bi  = b_ih[h]        + b_hh[h];
  const float bff = b_ih[1024 + h] + b_hh[1024 + h];
  const float bg  = b_ih[2048 + h] + b_hh[2048 + h];
  const float bo2 = b_ih[3072 + h] + b_hh[3072 + h];
  const float bd  = b_d[h];
#pragma unroll
  for (int mf = 0; mf < 4; ++mf) {
#pragma unroll
    for (int r = 0; r < 4; ++r) {
      const int m = m0 + wr * 64 + mf * 16 + fq * 4 + r;
      const float tv = t[m];
      const float T = (tv != 0.0f) ? (1.0f / tv) : 0.0f;
      const float cst = tanh_f(dacc[mf][r] + bd);
      const float cadj = cx[(long)m * 1024 + h] + (T - 1.0f) * cst;
      const float ig = sigm_f(acc[mf][0][r] + bi);
      const float fg = sigm_f(acc[mf][1][r] + bff);
      const float cg = tanh_f(acc[mf][2][r] + bg);
      const float og = sigm_f(acc[mf][3][r] + bo2);
      const float cyv = fg * cadj + ig * cg;
      const float hyv = og * tanh_f(cyv);
      out[(long)m * 1024 + h] = hyv;
      out[4096L * 1024 + (long)m * 1024 + h] = cyv;
    }
  }
}

extern "C" void kernel_launch(void* const* d_in, const int* in_sizes, int n_in,
                              void* d_out, int out_size, void* d_ws, size_t ws_size,
                              hipStream_t stream) {
  const float* input = (const float*)d_in[0];
  const float* t     = (const float*)d_in[1];
  const float* hx    = (const float*)d_in[2];
  const float* cx    = (const float*)d_in[3];
  const float* w_ih  = (const float*)d_in[4];
  const float* w_hh  = (const float*)d_in[5];
  const float* b_ih  = (const float*)d_in[6];
  const float* b_hh  = (const float*)d_in[7];
  const float* Wd    = (const float*)d_in[8];
  const float* b_d   = (const float*)d_in[9];

  const long B = 4096, H = 1024, KX = 1536, NG = 4096;

  char* ws = (char*)d_ws;
  unsigned short* Xhi = (unsigned short*)ws; ws += B * KX * 2;
  unsigned short* Xlo = (unsigned short*)ws; ws += B * KX * 2;
  unsigned short* Whi = (unsigned short*)ws; ws += NG * KX * 2;
  unsigned short* Wlo = (unsigned short*)ws; ws += NG * KX * 2;
  unsigned short* Chi = (unsigned short*)ws; ws += B * H * 2;
  unsigned short* Clo = (unsigned short*)ws; ws += B * H * 2;
  unsigned short* Dhi = (unsigned short*)ws; ws += H * H * 2;
  unsigned short* Dlo = (unsigned short*)ws; ws += H * H * 2;

  // 1: hi/lo splits (X+cx batched-MLP, W 16-h gate-interleaved, Wlo only for
  //    g in {1,2}) + W_decomp transpose
  prep_k<<<2304, 384, 0, stream>>>(input, hx, w_ih, w_hh, cx, Wd,
                                   Xhi, Xlo, Whi, Wlo, Chi, Clo, Dhi, Dlo);
  // 2: mega GEMM (decomp + gates gate-selective + full pointwise epilogue)
  gemm_mega<<<1024, 256, 0, stream>>>(Xhi, Xlo, Whi, Wlo, Chi, Clo, Dhi, Dlo,
                                      b_ih, b_hh, b_d, cx, t, (float*)d_out);
}